// Round 1
// baseline (196.284 us; speedup 1.0000x reference)
//
#include <hip/hip_runtime.h>
#include <math.h>

#define ALPHA   0.5f
#define BATA    0.01f
#define LAMDA   0.01f
#define GAMA    0.01f
#define BB      4096
#define N_NEG   50
#define TOTAL_H 204800
#define DIM     64

__device__ __forceinline__ float wave_reduce_sum(float v) {
    #pragma unroll
    for (int off = 32; off > 0; off >>= 1) v += __shfl_xor(v, off, 64);
    return v;
}

// One wave (64 threads) per user. lane = dim index.
__global__ __launch_bounds__(64) void fism_kernel(
    const float* __restrict__ bu, const float* __restrict__ bi,
    const float* __restrict__ qi, const float* __restrict__ pu,
    const float* __restrict__ user_item_num,
    const int*  __restrict__ users, const int* __restrict__ pos_items,
    const int*  __restrict__ neg_items, const int* __restrict__ hist_items,
    const int*  __restrict__ hist_segids,
    float* __restrict__ out)
{
    const int b    = blockIdx.x;
    const int lane = threadIdx.x;   // 0..63 == dim

    // --- binary search for history range [start, end) of segid == b (sorted) ---
    int lo = 0, hi = TOTAL_H;
    while (lo < hi) { int mid = (lo + hi) >> 1; if (hist_segids[mid] <  b) lo = mid + 1; else hi = mid; }
    const int start = lo;
    hi = TOTAL_H;
    while (lo < hi) { int mid = (lo + hi) >> 1; if (hist_segids[mid] <= b) lo = mid + 1; else hi = mid; }
    const int end = lo;

    // --- embedding-bag sum: user_embeds[b][lane] in a register ---
    float acc0 = 0.f, acc1 = 0.f;
    int i = start;
    for (; i + 2 <= end; i += 2) {
        int it0 = hist_items[i];
        int it1 = hist_items[i + 1];
        acc0 += pu[(size_t)it0 * DIM + lane];
        acc1 += pu[(size_t)it1 * DIM + lane];
    }
    if (i < end) acc0 += pu[(size_t)hist_items[i] * DIM + lane];
    const float acc = acc0 + acc1;

    const float t   = rsqrtf(user_item_num[b]);     // n^(-ALPHA), ALPHA=0.5
    const int   u   = users[b];
    const float b_u = bu[u];

    // --- positive item ---
    const int   pit  = pos_items[b];
    const float qd   = qi[(size_t)pit * DIM + lane];
    const float pdot = wave_reduce_sum(acc * qd);
    const float psq  = wave_reduce_sum(qd * qd);
    const float uesq = wave_reduce_sum(acc * acc);
    const float b_ip = bi[pit];

    float x = t * pdot + b_ip + b_u;
    float s = 1.f / (1.f + __expf(-x));
    float loss = (1.f - s) * (1.f - s);
    loss += BATA * uesq;
    loss += BATA * psq;
    loss += LAMDA * (b_ip * b_ip + GAMA * b_u * b_u);

    // --- negatives, unrolled x2 for ILP across the shuffle-reduce chains ---
    const int* nrow = neg_items + (size_t)b * N_NEG;
    #pragma unroll 1
    for (int n = 0; n < N_NEG; n += 2) {
        int i0 = nrow[n], i1 = nrow[n + 1];
        float q0 = qi[(size_t)i0 * DIM + lane];
        float q1 = qi[(size_t)i1 * DIM + lane];
        float d0 = acc * q0;
        float d1 = acc * q1;
        #pragma unroll
        for (int off = 32; off > 0; off >>= 1) {
            d0 += __shfl_xor(d0, off, 64);
            d1 += __shfl_xor(d1, off, 64);
        }
        float bj0 = bi[i0], bj1 = bi[i1];
        float s0 = 1.f / (1.f + __expf(-(t * d0 + bj0 + b_u)));
        float s1 = 1.f / (1.f + __expf(-(t * d1 + bj1 + b_u)));
        loss += s0 * s0 + s1 * s1;
    }

    if (lane == 0) atomicAdd(out, loss);
}

extern "C" void kernel_launch(void* const* d_in, const int* in_sizes, int n_in,
                              void* d_out, int out_size, void* d_ws, size_t ws_size,
                              hipStream_t stream) {
    const float* bu            = (const float*)d_in[0];
    const float* bi            = (const float*)d_in[1];
    const float* qi            = (const float*)d_in[2];
    const float* pu            = (const float*)d_in[3];
    const float* user_item_num = (const float*)d_in[4];
    const int*   users         = (const int*)d_in[5];
    const int*   pos_items     = (const int*)d_in[6];
    const int*   neg_items     = (const int*)d_in[7];
    const int*   hist_items    = (const int*)d_in[8];
    const int*   hist_segids   = (const int*)d_in[9];
    float* out = (float*)d_out;

    hipMemsetAsync(out, 0, sizeof(float), stream);
    fism_kernel<<<BB, 64, 0, stream>>>(bu, bi, qi, pu, user_item_num,
                                       users, pos_items, neg_items,
                                       hist_items, hist_segids, out);
}

// Round 2
// 175.898 us; speedup vs baseline: 1.1159x; 1.1159x over previous
//
#include <hip/hip_runtime.h>
#include <math.h>

#define ALPHA   0.5f
#define BATA    0.01f
#define LAMDA   0.01f
#define GAMA    0.01f
#define BB      4096
#define N_NEG   50
#define TOTAL_H 204800
#define DIM     64

// One 256-thread block (4 waves) per user.
// 16-lane "groups" (g = tid/16, sub = tid%16) each own a 64-dim row via float4:
// lane sub covers dims [sub*4, sub*4+4). 16 groups stride over history rows /
// scored items, giving 4 rows in flight per wave-instruction.
__global__ __launch_bounds__(256) void fism_kernel(
    const float* __restrict__ bu, const float* __restrict__ bi,
    const float* __restrict__ qi, const float* __restrict__ pu,
    const float* __restrict__ user_item_num,
    const int*  __restrict__ users, const int* __restrict__ pos_items,
    const int*  __restrict__ neg_items, const int* __restrict__ hist_items,
    const int*  __restrict__ hist_segids,
    float* __restrict__ out)
{
    const int b    = blockIdx.x;
    const int tid  = threadIdx.x;
    const int lane = tid & 63;
    const int w    = tid >> 6;    // wave 0..3
    const int g    = tid >> 4;    // group 0..15
    const int sub  = tid & 15;    // lane-in-group == dim-chunk

    __shared__ float4 s_part[64];   // [wave*16 + sub] partial user-embed
    __shared__ float  s_loss[4];

    // --- binary search (uniform across block; scalarized) ---
    int lo = 0, hi = TOTAL_H;
    while (lo < hi) { int mid = (lo + hi) >> 1; if (hist_segids[mid] <  b) lo = mid + 1; else hi = mid; }
    const int start = lo;
    hi = TOTAL_H;
    while (lo < hi) { int mid = (lo + hi) >> 1; if (hist_segids[mid] <= b) lo = mid + 1; else hi = mid; }
    const int end = lo;

    const float4* pu4 = (const float4*)pu;
    const float4* qi4 = (const float4*)qi;

    // --- embedding-bag: groups stride over history rows, unroll x2 ---
    float4 acc = make_float4(0.f, 0.f, 0.f, 0.f);
    int i = start + g;
    for (; i + 16 < end; i += 32) {
        int it0 = hist_items[i];
        int it1 = hist_items[i + 16];
        float4 r0 = pu4[(size_t)it0 * 16 + sub];
        float4 r1 = pu4[(size_t)it1 * 16 + sub];
        acc.x += r0.x + r1.x; acc.y += r0.y + r1.y;
        acc.z += r0.z + r1.z; acc.w += r0.w + r1.w;
    }
    if (i < end) {
        float4 r = pu4[(size_t)hist_items[i] * 16 + sub];
        acc.x += r.x; acc.y += r.y; acc.z += r.z; acc.w += r.w;
    }

    // reduce the 4 groups within this wave (xor lane bits 4,5)
    #pragma unroll
    for (int off = 16; off < 64; off <<= 1) {
        acc.x += __shfl_xor(acc.x, off, 64);
        acc.y += __shfl_xor(acc.y, off, 64);
        acc.z += __shfl_xor(acc.z, off, 64);
        acc.w += __shfl_xor(acc.w, off, 64);
    }
    if (lane < 16) s_part[w * 16 + lane] = acc;
    __syncthreads();

    // every lane picks up the full user embedding for its dim-chunk
    float4 full = s_part[sub];
    {
        float4 p1 = s_part[16 + sub], p2 = s_part[32 + sub], p3 = s_part[48 + sub];
        full.x += p1.x + p2.x + p3.x;
        full.y += p1.y + p2.y + p3.y;
        full.z += p1.z + p2.z + p3.z;
        full.w += p1.w + p2.w + p3.w;
    }

    const float t   = rsqrtf(user_item_num[b]);   // n^(-0.5)
    const float b_u = bu[users[b]];
    const int* nrow = neg_items + (size_t)b * N_NEG;

    float loss = 0.f;

    // --- positive item + per-user terms (computed redundantly per group, added once) ---
    {
        const int   pit = pos_items[b];
        const float bip = bi[pit];
        float4 q = qi4[(size_t)pit * 16 + sub];
        float pdot = full.x * q.x + full.y * q.y + full.z * q.z + full.w * q.w;
        float psq  = q.x * q.x + q.y * q.y + q.z * q.z + q.w * q.w;
        float uesq = full.x * full.x + full.y * full.y + full.z * full.z + full.w * full.w;
        #pragma unroll
        for (int off = 1; off < 16; off <<= 1) {
            pdot += __shfl_xor(pdot, off, 64);
            psq  += __shfl_xor(psq,  off, 64);
            uesq += __shfl_xor(uesq, off, 64);
        }
        if (tid == 0) {
            float s = 1.f / (1.f + __expf(-(t * pdot + bip + b_u)));
            loss += (1.f - s) * (1.f - s);
            loss += BATA * uesq + BATA * psq;
            loss += LAMDA * (bip * bip + GAMA * b_u * b_u);
        }
    }

    // --- negatives: groups stride over the 50 items, unroll x2 ---
    int j = g;
    for (; j + 16 < N_NEG; j += 32) {
        int i0 = nrow[j], i1 = nrow[j + 16];
        float bj0 = bi[i0], bj1 = bi[i1];
        float4 q0 = qi4[(size_t)i0 * 16 + sub];
        float4 q1 = qi4[(size_t)i1 * 16 + sub];
        float d0 = full.x * q0.x + full.y * q0.y + full.z * q0.z + full.w * q0.w;
        float d1 = full.x * q1.x + full.y * q1.y + full.z * q1.z + full.w * q1.w;
        #pragma unroll
        for (int off = 1; off < 16; off <<= 1) {
            d0 += __shfl_xor(d0, off, 64);
            d1 += __shfl_xor(d1, off, 64);
        }
        if (sub == 0) {
            float s0 = 1.f / (1.f + __expf(-(t * d0 + bj0 + b_u)));
            float s1 = 1.f / (1.f + __expf(-(t * d1 + bj1 + b_u)));
            loss += s0 * s0 + s1 * s1;
        }
    }
    if (j < N_NEG) {
        int i0 = nrow[j];
        float bj0 = bi[i0];
        float4 q0 = qi4[(size_t)i0 * 16 + sub];
        float d0 = full.x * q0.x + full.y * q0.y + full.z * q0.z + full.w * q0.w;
        #pragma unroll
        for (int off = 1; off < 16; off <<= 1) d0 += __shfl_xor(d0, off, 64);
        if (sub == 0) {
            float s0 = 1.f / (1.f + __expf(-(t * d0 + bj0 + b_u)));
            loss += s0 * s0;
        }
    }

    // --- block reduction of loss (nonzero only at sub==0 lanes) ---
    #pragma unroll
    for (int off = 32; off > 0; off >>= 1) loss += __shfl_xor(loss, off, 64);
    if (lane == 0) s_loss[w] = loss;
    __syncthreads();
    if (tid == 0) {
        float tot = s_loss[0] + s_loss[1] + s_loss[2] + s_loss[3];
        atomicAdd(out, tot);
    }
}

extern "C" void kernel_launch(void* const* d_in, const int* in_sizes, int n_in,
                              void* d_out, int out_size, void* d_ws, size_t ws_size,
                              hipStream_t stream) {
    const float* bu            = (const float*)d_in[0];
    const float* bi            = (const float*)d_in[1];
    const float* qi            = (const float*)d_in[2];
    const float* pu            = (const float*)d_in[3];
    const float* user_item_num = (const float*)d_in[4];
    const int*   users         = (const int*)d_in[5];
    const int*   pos_items     = (const int*)d_in[6];
    const int*   neg_items     = (const int*)d_in[7];
    const int*   hist_items    = (const int*)d_in[8];
    const int*   hist_segids   = (const int*)d_in[9];
    float* out = (float*)d_out;

    hipMemsetAsync(out, 0, sizeof(float), stream);
    fism_kernel<<<BB, 256, 0, stream>>>(bu, bi, qi, pu, user_item_num,
                                        users, pos_items, neg_items,
                                        hist_items, hist_segids, out);
}

// Round 3
// 168.165 us; speedup vs baseline: 1.1672x; 1.0460x over previous
//
#include <hip/hip_runtime.h>
#include <math.h>

#define ALPHA   0.5f
#define BATA    0.01f
#define LAMDA   0.01f
#define GAMA    0.01f
#define BB      4096
#define N_NEG   50
#define TOTAL_H 204800
#define DIM     64

// ---------------- phase 0: segment offsets (kills the per-block binary search)
// offs[b] = first index i with hist_segids[i] >= b ; offs[BB] = TOTAL_H.
__global__ __launch_bounds__(256) void offs_kernel(
    const int* __restrict__ segids, int* __restrict__ offs)
{
    int i = blockIdx.x * 256 + threadIdx.x;
    if (i >= TOTAL_H) return;
    int s = segids[i];
    if (i == 0) {
        for (int b = 0; b <= s; ++b) offs[b] = 0;
    } else {
        int p = segids[i - 1];
        for (int b = p + 1; b <= s; ++b) offs[b] = i;
    }
    if (i == TOTAL_H - 1) {
        for (int b = s + 1; b <= BB; ++b) offs[b] = TOTAL_H;
    }
}

// ---------------- main: one 256-thread block (4 waves) per user.
// 16-lane groups (g = tid/16, sub = tid%16); lane sub owns dims [4*sub,4*sub+4).
__global__ __launch_bounds__(256) void fism_kernel(
    const float* __restrict__ bu, const float* __restrict__ bi,
    const float* __restrict__ qi, const float* __restrict__ pu,
    const float* __restrict__ user_item_num,
    const int*  __restrict__ users, const int* __restrict__ pos_items,
    const int*  __restrict__ neg_items, const int* __restrict__ hist_items,
    const int*  __restrict__ offs,
    float* __restrict__ out)
{
    const int b    = blockIdx.x;
    const int tid  = threadIdx.x;
    const int lane = tid & 63;
    const int w    = tid >> 6;
    const int g    = tid >> 4;
    const int sub  = tid & 15;

    __shared__ float4 s_part[64];
    __shared__ float  s_loss[4];

    const float4* pu4 = (const float4*)pu;
    const float4* qi4 = (const float4*)qi;

    const int start = offs[b];
    const int end   = offs[b + 1];

    // ---- prefetch: negative rows/biases + positive row + scalars.
    // These loads are independent of the hist bag and fly concurrently with it.
    const int* nrow = neg_items + (size_t)b * N_NEG;
    int   nidx[4];
    bool  nv[4];
    #pragma unroll
    for (int k = 0; k < 4; ++k) {
        int j = g + 16 * k;
        nv[k]   = (j < N_NEG);
        nidx[k] = nrow[nv[k] ? j : 0];
    }
    float4 nq[4];
    float  nb[4];
    #pragma unroll
    for (int k = 0; k < 4; ++k) {
        nq[k] = qi4[(size_t)nidx[k] * 16 + sub];
        nb[k] = bi[nidx[k]];
    }
    const int    pit = pos_items[b];
    const float4 qp  = qi4[(size_t)pit * 16 + sub];
    const float  bip = bi[pit];
    const float  t   = rsqrtf(user_item_num[b]);
    const float  b_u = bu[users[b]];

    // ---- embedding-bag: groups stride over history rows, unroll x2
    float4 acc = make_float4(0.f, 0.f, 0.f, 0.f);
    int i = start + g;
    for (; i + 16 < end; i += 32) {
        int it0 = hist_items[i];
        int it1 = hist_items[i + 16];
        float4 r0 = pu4[(size_t)it0 * 16 + sub];
        float4 r1 = pu4[(size_t)it1 * 16 + sub];
        acc.x += r0.x + r1.x; acc.y += r0.y + r1.y;
        acc.z += r0.z + r1.z; acc.w += r0.w + r1.w;
    }
    if (i < end) {
        float4 r = pu4[(size_t)hist_items[i] * 16 + sub];
        acc.x += r.x; acc.y += r.y; acc.z += r.z; acc.w += r.w;
    }

    // reduce the 4 groups within this wave (xor lane bits 4,5)
    #pragma unroll
    for (int off = 16; off < 64; off <<= 1) {
        acc.x += __shfl_xor(acc.x, off, 64);
        acc.y += __shfl_xor(acc.y, off, 64);
        acc.z += __shfl_xor(acc.z, off, 64);
        acc.w += __shfl_xor(acc.w, off, 64);
    }
    if (lane < 16) s_part[w * 16 + lane] = acc;
    __syncthreads();

    float4 full = s_part[sub];
    {
        float4 p1 = s_part[16 + sub], p2 = s_part[32 + sub], p3 = s_part[48 + sub];
        full.x += p1.x + p2.x + p3.x;
        full.y += p1.y + p2.y + p3.y;
        full.z += p1.z + p2.z + p3.z;
        full.w += p1.w + p2.w + p3.w;
    }

    float loss = 0.f;

    // ---- positive + per-user regularization terms
    {
        float pdot = full.x * qp.x + full.y * qp.y + full.z * qp.z + full.w * qp.w;
        float psq  = qp.x * qp.x + qp.y * qp.y + qp.z * qp.z + qp.w * qp.w;
        float uesq = full.x * full.x + full.y * full.y + full.z * full.z + full.w * full.w;
        #pragma unroll
        for (int off = 1; off < 16; off <<= 1) {
            pdot += __shfl_xor(pdot, off, 64);
            psq  += __shfl_xor(psq,  off, 64);
            uesq += __shfl_xor(uesq, off, 64);
        }
        if (tid == 0) {
            float s = 1.f / (1.f + __expf(-(t * pdot + bip + b_u)));
            loss += (1.f - s) * (1.f - s);
            loss += BATA * uesq + BATA * psq;
            loss += LAMDA * (bip * bip + GAMA * b_u * b_u);
        }
    }

    // ---- negatives: all rows already in registers; 4 interleaved reduce chains
    {
        float d0 = full.x * nq[0].x + full.y * nq[0].y + full.z * nq[0].z + full.w * nq[0].w;
        float d1 = full.x * nq[1].x + full.y * nq[1].y + full.z * nq[1].z + full.w * nq[1].w;
        float d2 = full.x * nq[2].x + full.y * nq[2].y + full.z * nq[2].z + full.w * nq[2].w;
        float d3 = full.x * nq[3].x + full.y * nq[3].y + full.z * nq[3].z + full.w * nq[3].w;
        #pragma unroll
        for (int off = 1; off < 16; off <<= 1) {
            d0 += __shfl_xor(d0, off, 64);
            d1 += __shfl_xor(d1, off, 64);
            d2 += __shfl_xor(d2, off, 64);
            d3 += __shfl_xor(d3, off, 64);
        }
        if (sub == 0) {
            float s0 = 1.f / (1.f + __expf(-(t * d0 + nb[0] + b_u)));
            float s1 = 1.f / (1.f + __expf(-(t * d1 + nb[1] + b_u)));
            float s2 = 1.f / (1.f + __expf(-(t * d2 + nb[2] + b_u)));
            float s3 = 1.f / (1.f + __expf(-(t * d3 + nb[3] + b_u)));
            if (nv[0]) loss += s0 * s0;
            if (nv[1]) loss += s1 * s1;
            if (nv[2]) loss += s2 * s2;
            if (nv[3]) loss += s3 * s3;
        }
    }

    // ---- block loss reduction
    #pragma unroll
    for (int off = 32; off > 0; off >>= 1) loss += __shfl_xor(loss, off, 64);
    if (lane == 0) s_loss[w] = loss;
    __syncthreads();
    if (tid == 0) {
        atomicAdd(out, s_loss[0] + s_loss[1] + s_loss[2] + s_loss[3]);
    }
}

extern "C" void kernel_launch(void* const* d_in, const int* in_sizes, int n_in,
                              void* d_out, int out_size, void* d_ws, size_t ws_size,
                              hipStream_t stream) {
    const float* bu            = (const float*)d_in[0];
    const float* bi            = (const float*)d_in[1];
    const float* qi            = (const float*)d_in[2];
    const float* pu            = (const float*)d_in[3];
    const float* user_item_num = (const float*)d_in[4];
    const int*   users         = (const int*)d_in[5];
    const int*   pos_items     = (const int*)d_in[6];
    const int*   neg_items     = (const int*)d_in[7];
    const int*   hist_items    = (const int*)d_in[8];
    const int*   hist_segids   = (const int*)d_in[9];
    float* out  = (float*)d_out;
    int*   offs = (int*)d_ws;            // (BB+1) ints

    hipMemsetAsync(out, 0, sizeof(float), stream);
    offs_kernel<<<(TOTAL_H + 255) / 256, 256, 0, stream>>>(hist_segids, offs);
    fism_kernel<<<BB, 256, 0, stream>>>(bu, bi, qi, pu, user_item_num,
                                        users, pos_items, neg_items,
                                        hist_items, offs, out);
}

// Round 4
// 129.996 us; speedup vs baseline: 1.5099x; 1.2936x over previous
//
#include <hip/hip_runtime.h>
#include <math.h>

#define ALPHA   0.5f
#define BATA    0.01f
#define LAMDA   0.01f
#define GAMA    0.01f
#define BB      4096
#define N_NEG   50
#define TOTAL_H 204800
#define DIM     64

// ---------------- phase 0: segment offsets
// offs[b] = first index i with hist_segids[i] >= b ; offs[BB] = TOTAL_H.
__global__ __launch_bounds__(256) void offs_kernel(
    const int* __restrict__ segids, int* __restrict__ offs)
{
    int i = blockIdx.x * 256 + threadIdx.x;
    if (i >= TOTAL_H) return;
    int s = segids[i];
    if (i == 0) {
        for (int b = 0; b <= s; ++b) offs[b] = 0;
    } else {
        int p = segids[i - 1];
        for (int b = p + 1; b <= s; ++b) offs[b] = i;
    }
    if (i == TOTAL_H - 1) {
        for (int b = s + 1; b <= BB; ++b) offs[b] = TOTAL_H;
    }
}

// ---------------- main: one 256-thread block (4 waves) per user.
// 16-lane groups (g = tid/16, sub = tid%16); lane sub owns dims [4*sub,4*sub+4).
// NO global atomics: per-block partial loss -> part[b].
__global__ __launch_bounds__(256) void fism_kernel(
    const float* __restrict__ bu, const float* __restrict__ bi,
    const float* __restrict__ qi, const float* __restrict__ pu,
    const float* __restrict__ user_item_num,
    const int*  __restrict__ users, const int* __restrict__ pos_items,
    const int*  __restrict__ neg_items, const int* __restrict__ hist_items,
    const int*  __restrict__ offs,
    float* __restrict__ part)
{
    const int b    = blockIdx.x;
    const int tid  = threadIdx.x;
    const int lane = tid & 63;
    const int w    = tid >> 6;
    const int g    = tid >> 4;
    const int sub  = tid & 15;

    __shared__ float4 s_part[64];
    __shared__ float  s_loss[4];

    const float4* pu4 = (const float4*)pu;
    const float4* qi4 = (const float4*)qi;

    const int start = offs[b];
    const int end   = offs[b + 1];

    // ---- prefetch negatives + positive (independent of hist chain)
    const int* nrow = neg_items + (size_t)b * N_NEG;
    int   nidx[4];
    bool  nv[4];
    #pragma unroll
    for (int k = 0; k < 4; ++k) {
        int j = g + 16 * k;
        nv[k]   = (j < N_NEG);
        nidx[k] = nrow[nv[k] ? j : 0];
    }
    float4 nq[4];
    float  nb[4];
    #pragma unroll
    for (int k = 0; k < 4; ++k) {
        nq[k] = qi4[(size_t)nidx[k] * 16 + sub];
        nb[k] = bi[nidx[k]];
    }
    const int    pit = pos_items[b];
    const float4 qp  = qi4[(size_t)pit * 16 + sub];
    const float  bip = bi[pit];
    const float  t   = rsqrtf(user_item_num[b]);
    const float  b_u = bu[users[b]];

    // ---- embedding-bag: batch-issue 4 gathers per iteration
    float4 acc = make_float4(0.f, 0.f, 0.f, 0.f);
    int i = start + g;
    for (; i + 48 < end; i += 64) {
        int it0 = hist_items[i];
        int it1 = hist_items[i + 16];
        int it2 = hist_items[i + 32];
        int it3 = hist_items[i + 48];
        float4 r0 = pu4[(size_t)it0 * 16 + sub];
        float4 r1 = pu4[(size_t)it1 * 16 + sub];
        float4 r2 = pu4[(size_t)it2 * 16 + sub];
        float4 r3 = pu4[(size_t)it3 * 16 + sub];
        acc.x += (r0.x + r1.x) + (r2.x + r3.x);
        acc.y += (r0.y + r1.y) + (r2.y + r3.y);
        acc.z += (r0.z + r1.z) + (r2.z + r3.z);
        acc.w += (r0.w + r1.w) + (r2.w + r3.w);
    }
    // masked tail: up to 3 more entries for this group
    {
        bool v0 = i      < end;
        bool v1 = i + 16 < end;
        bool v2 = i + 32 < end;
        int it0 = v0 ? hist_items[i]      : 0;
        int it1 = v1 ? hist_items[i + 16] : 0;
        int it2 = v2 ? hist_items[i + 32] : 0;
        float4 r0 = pu4[(size_t)it0 * 16 + sub];
        float4 r1 = pu4[(size_t)it1 * 16 + sub];
        float4 r2 = pu4[(size_t)it2 * 16 + sub];
        float m0 = v0 ? 1.f : 0.f, m1 = v1 ? 1.f : 0.f, m2 = v2 ? 1.f : 0.f;
        acc.x += m0 * r0.x + m1 * r1.x + m2 * r2.x;
        acc.y += m0 * r0.y + m1 * r1.y + m2 * r2.y;
        acc.z += m0 * r0.z + m1 * r1.z + m2 * r2.z;
        acc.w += m0 * r0.w + m1 * r1.w + m2 * r2.w;
        // safety catch-all (never runs for avg-50 histories; correctness guard)
        for (int ii = i + 48; ii < end; ii += 16) {
            float4 r = pu4[(size_t)hist_items[ii] * 16 + sub];
            acc.x += r.x; acc.y += r.y; acc.z += r.z; acc.w += r.w;
        }
    }

    // reduce the 4 groups within this wave (xor lane bits 4,5)
    #pragma unroll
    for (int off = 16; off < 64; off <<= 1) {
        acc.x += __shfl_xor(acc.x, off, 64);
        acc.y += __shfl_xor(acc.y, off, 64);
        acc.z += __shfl_xor(acc.z, off, 64);
        acc.w += __shfl_xor(acc.w, off, 64);
    }
    if (lane < 16) s_part[w * 16 + lane] = acc;
    __syncthreads();

    float4 full = s_part[sub];
    {
        float4 p1 = s_part[16 + sub], p2 = s_part[32 + sub], p3 = s_part[48 + sub];
        full.x += p1.x + p2.x + p3.x;
        full.y += p1.y + p2.y + p3.y;
        full.z += p1.z + p2.z + p3.z;
        full.w += p1.w + p2.w + p3.w;
    }

    float loss = 0.f;

    // ---- positive + per-user regularization
    {
        float pdot = full.x * qp.x + full.y * qp.y + full.z * qp.z + full.w * qp.w;
        float psq  = qp.x * qp.x + qp.y * qp.y + qp.z * qp.z + qp.w * qp.w;
        float uesq = full.x * full.x + full.y * full.y + full.z * full.z + full.w * full.w;
        #pragma unroll
        for (int off = 1; off < 16; off <<= 1) {
            pdot += __shfl_xor(pdot, off, 64);
            psq  += __shfl_xor(psq,  off, 64);
            uesq += __shfl_xor(uesq, off, 64);
        }
        if (tid == 0) {
            float s = 1.f / (1.f + __expf(-(t * pdot + bip + b_u)));
            loss += (1.f - s) * (1.f - s);
            loss += BATA * uesq + BATA * psq;
            loss += LAMDA * (bip * bip + GAMA * b_u * b_u);
        }
    }

    // ---- negatives: rows already in registers; 4 interleaved reduce chains
    {
        float d0 = full.x * nq[0].x + full.y * nq[0].y + full.z * nq[0].z + full.w * nq[0].w;
        float d1 = full.x * nq[1].x + full.y * nq[1].y + full.z * nq[1].z + full.w * nq[1].w;
        float d2 = full.x * nq[2].x + full.y * nq[2].y + full.z * nq[2].z + full.w * nq[2].w;
        float d3 = full.x * nq[3].x + full.y * nq[3].y + full.z * nq[3].z + full.w * nq[3].w;
        #pragma unroll
        for (int off = 1; off < 16; off <<= 1) {
            d0 += __shfl_xor(d0, off, 64);
            d1 += __shfl_xor(d1, off, 64);
            d2 += __shfl_xor(d2, off, 64);
            d3 += __shfl_xor(d3, off, 64);
        }
        if (sub == 0) {
            float s0 = 1.f / (1.f + __expf(-(t * d0 + nb[0] + b_u)));
            float s1 = 1.f / (1.f + __expf(-(t * d1 + nb[1] + b_u)));
            float s2 = 1.f / (1.f + __expf(-(t * d2 + nb[2] + b_u)));
            float s3 = 1.f / (1.f + __expf(-(t * d3 + nb[3] + b_u)));
            if (nv[0]) loss += s0 * s0;
            if (nv[1]) loss += s1 * s1;
            if (nv[2]) loss += s2 * s2;
            if (nv[3]) loss += s3 * s3;
        }
    }

    // ---- block loss reduction: only lanes 0/16/32/48 are nonzero -> 2 levels
    loss += __shfl_xor(loss, 16, 64);
    loss += __shfl_xor(loss, 32, 64);
    if (lane == 0) s_loss[w] = loss;
    __syncthreads();
    if (tid == 0) part[b] = s_loss[0] + s_loss[1] + s_loss[2] + s_loss[3];
}

// ---------------- final: sum 4096 partials -> out[0] (single block, no atomics)
__global__ __launch_bounds__(256) void reduce_kernel(
    const float* __restrict__ part, float* __restrict__ out)
{
    const int tid  = threadIdx.x;
    const int lane = tid & 63;
    const int w    = tid >> 6;
    float s = 0.f;
    #pragma unroll
    for (int i = 0; i < BB / 256; ++i) s += part[tid + i * 256];
    #pragma unroll
    for (int off = 32; off > 0; off >>= 1) s += __shfl_xor(s, off, 64);
    __shared__ float sl[4];
    if (lane == 0) sl[w] = s;
    __syncthreads();
    if (tid == 0) out[0] = sl[0] + sl[1] + sl[2] + sl[3];
}

extern "C" void kernel_launch(void* const* d_in, const int* in_sizes, int n_in,
                              void* d_out, int out_size, void* d_ws, size_t ws_size,
                              hipStream_t stream) {
    const float* bu            = (const float*)d_in[0];
    const float* bi            = (const float*)d_in[1];
    const float* qi            = (const float*)d_in[2];
    const float* pu            = (const float*)d_in[3];
    const float* user_item_num = (const float*)d_in[4];
    const int*   users         = (const int*)d_in[5];
    const int*   pos_items     = (const int*)d_in[6];
    const int*   neg_items     = (const int*)d_in[7];
    const int*   hist_items    = (const int*)d_in[8];
    const int*   hist_segids   = (const int*)d_in[9];
    float* out  = (float*)d_out;

    int*   offs = (int*)d_ws;                         // BB+1 ints
    float* part = (float*)((char*)d_ws + ((BB + 2) * sizeof(int) + 255 & ~255)); // BB floats

    offs_kernel<<<(TOTAL_H + 255) / 256, 256, 0, stream>>>(hist_segids, offs);
    fism_kernel<<<BB, 256, 0, stream>>>(bu, bi, qi, pu, user_item_num,
                                        users, pos_items, neg_items,
                                        hist_items, offs, part);
    reduce_kernel<<<1, 256, 0, stream>>>(part, out);
}

// Round 5
// 129.692 us; speedup vs baseline: 1.5135x; 1.0023x over previous
//
#include <hip/hip_runtime.h>
#include <math.h>

#define ALPHA   0.5f
#define BATA    0.01f
#define LAMDA   0.01f
#define GAMA    0.01f
#define BB      4096
#define N_NEG   50
#define TOTAL_H 204800
#define DIM     64

// ---------------- phase 0: segment offsets
// offs[b] = first index i with hist_segids[i] >= b ; offs[BB] = TOTAL_H.
__global__ __launch_bounds__(256) void offs_kernel(
    const int* __restrict__ segids, int* __restrict__ offs)
{
    int i = blockIdx.x * 256 + threadIdx.x;
    if (i >= TOTAL_H) return;
    int s = segids[i];
    if (i == 0) {
        for (int b = 0; b <= s; ++b) offs[b] = 0;
    } else {
        int p = segids[i - 1];
        for (int b = p + 1; b <= s; ++b) offs[b] = i;
    }
    if (i == TOTAL_H - 1) {
        for (int b = s + 1; b <= BB; ++b) offs[b] = TOTAL_H;
    }
}

// ---------------- main: one 256-thread block (4 waves) per user.
// 16-lane groups (g = tid/16, sub = tid%16); lane sub owns dims [4*sub,4*sub+4).
// TWO memory tiers only: (1) all indices, (2) all row gathers (13/thread in flight).
__global__ __launch_bounds__(256) void fism_kernel(
    const float* __restrict__ bu, const float* __restrict__ bi,
    const float* __restrict__ qi, const float* __restrict__ pu,
    const float* __restrict__ user_item_num,
    const int*  __restrict__ users, const int* __restrict__ pos_items,
    const int*  __restrict__ neg_items, const int* __restrict__ hist_items,
    const int*  __restrict__ offs,
    float* __restrict__ part)
{
    const int b    = blockIdx.x;
    const int tid  = threadIdx.x;
    const int lane = tid & 63;
    const int w    = tid >> 6;
    const int g    = tid >> 4;
    const int sub  = tid & 15;

    __shared__ float4 s_part[64];
    __shared__ float  s_loss[4];

    const float4* pu4 = (const float4*)pu;
    const float4* qi4 = (const float4*)qi;

    const int start = offs[b];
    const int end   = offs[b + 1];

    // ---- tier 1: ALL index / scalar loads (no dependence among them)
    const int* nrow = neg_items + (size_t)b * N_NEG;
    int  nidx[4];
    bool nv[4];
    #pragma unroll
    for (int k = 0; k < 4; ++k) {
        int j = g + 16 * k;
        nv[k]   = (j < N_NEG);
        nidx[k] = nrow[nv[k] ? j : 0];
    }
    const int   pit = pos_items[b];
    const float t   = rsqrtf(user_item_num[b]);
    const float b_u = bu[users[b]];

    // masked preload of up to 8 hist indices per group (covers histories <= 128)
    int   hidx[8];
    float hm[8];
    #pragma unroll
    for (int k = 0; k < 8; ++k) {
        int ip   = start + g + 16 * k;
        bool v   = (ip < end);
        hm[k]    = v ? 1.f : 0.f;
        int ipc  = v ? ip : (TOTAL_H - 1);       // always in-bounds
        hidx[k]  = hist_items[ipc];
    }

    // ---- tier 2: ALL row gathers, issued in consumption order
    // hist rows first (consumed first), then pos, then negs.
    float4 acc = make_float4(0.f, 0.f, 0.f, 0.f);
    #pragma unroll
    for (int k = 0; k < 8; ++k) {
        float4 r = pu4[(size_t)hidx[k] * 16 + sub];
        acc.x += hm[k] * r.x; acc.y += hm[k] * r.y;
        acc.z += hm[k] * r.z; acc.w += hm[k] * r.w;
    }
    const float4 qp  = qi4[(size_t)pit * 16 + sub];
    const float  bip = bi[pit];
    float4 nq[4];
    float  nb[4];
    #pragma unroll
    for (int k = 0; k < 4; ++k) {
        nq[k] = qi4[(size_t)nidx[k] * 16 + sub];
        nb[k] = bi[nidx[k]];
    }
    // correctness guard for histories > 128 (statistically never for this data)
    for (int i = start + g + 128; i < end; i += 16) {
        float4 r = pu4[(size_t)hist_items[i] * 16 + sub];
        acc.x += r.x; acc.y += r.y; acc.z += r.z; acc.w += r.w;
    }

    // reduce the 4 groups within this wave (xor lane bits 4,5)
    #pragma unroll
    for (int off = 16; off < 64; off <<= 1) {
        acc.x += __shfl_xor(acc.x, off, 64);
        acc.y += __shfl_xor(acc.y, off, 64);
        acc.z += __shfl_xor(acc.z, off, 64);
        acc.w += __shfl_xor(acc.w, off, 64);
    }
    if (lane < 16) s_part[w * 16 + lane] = acc;
    __syncthreads();

    float4 full = s_part[sub];
    {
        float4 p1 = s_part[16 + sub], p2 = s_part[32 + sub], p3 = s_part[48 + sub];
        full.x += p1.x + p2.x + p3.x;
        full.y += p1.y + p2.y + p3.y;
        full.z += p1.z + p2.z + p3.z;
        full.w += p1.w + p2.w + p3.w;
    }

    float loss = 0.f;

    // ---- positive + per-user regularization
    {
        float pdot = full.x * qp.x + full.y * qp.y + full.z * qp.z + full.w * qp.w;
        float psq  = qp.x * qp.x + qp.y * qp.y + qp.z * qp.z + qp.w * qp.w;
        float uesq = full.x * full.x + full.y * full.y + full.z * full.z + full.w * full.w;
        #pragma unroll
        for (int off = 1; off < 16; off <<= 1) {
            pdot += __shfl_xor(pdot, off, 64);
            psq  += __shfl_xor(psq,  off, 64);
            uesq += __shfl_xor(uesq, off, 64);
        }
        if (tid == 0) {
            float s = 1.f / (1.f + __expf(-(t * pdot + bip + b_u)));
            loss += (1.f - s) * (1.f - s);
            loss += BATA * uesq + BATA * psq;
            loss += LAMDA * (bip * bip + GAMA * b_u * b_u);
        }
    }

    // ---- negatives: rows already in registers; 4 interleaved reduce chains
    {
        float d0 = full.x * nq[0].x + full.y * nq[0].y + full.z * nq[0].z + full.w * nq[0].w;
        float d1 = full.x * nq[1].x + full.y * nq[1].y + full.z * nq[1].z + full.w * nq[1].w;
        float d2 = full.x * nq[2].x + full.y * nq[2].y + full.z * nq[2].z + full.w * nq[2].w;
        float d3 = full.x * nq[3].x + full.y * nq[3].y + full.z * nq[3].z + full.w * nq[3].w;
        #pragma unroll
        for (int off = 1; off < 16; off <<= 1) {
            d0 += __shfl_xor(d0, off, 64);
            d1 += __shfl_xor(d1, off, 64);
            d2 += __shfl_xor(d2, off, 64);
            d3 += __shfl_xor(d3, off, 64);
        }
        if (sub == 0) {
            float s0 = 1.f / (1.f + __expf(-(t * d0 + nb[0] + b_u)));
            float s1 = 1.f / (1.f + __expf(-(t * d1 + nb[1] + b_u)));
            float s2 = 1.f / (1.f + __expf(-(t * d2 + nb[2] + b_u)));
            float s3 = 1.f / (1.f + __expf(-(t * d3 + nb[3] + b_u)));
            if (nv[0]) loss += s0 * s0;
            if (nv[1]) loss += s1 * s1;
            if (nv[2]) loss += s2 * s2;
            if (nv[3]) loss += s3 * s3;
        }
    }

    // ---- block loss reduction: only lanes 0/16/32/48 are nonzero -> 2 levels
    loss += __shfl_xor(loss, 16, 64);
    loss += __shfl_xor(loss, 32, 64);
    if (lane == 0) s_loss[w] = loss;
    __syncthreads();
    if (tid == 0) part[b] = s_loss[0] + s_loss[1] + s_loss[2] + s_loss[3];
}

// ---------------- final: sum 4096 partials -> out[0] (single block, no atomics)
__global__ __launch_bounds__(256) void reduce_kernel(
    const float* __restrict__ part, float* __restrict__ out)
{
    const int tid  = threadIdx.x;
    const int lane = tid & 63;
    const int w    = tid >> 6;
    float s = 0.f;
    #pragma unroll
    for (int i = 0; i < BB / 256; ++i) s += part[tid + i * 256];
    #pragma unroll
    for (int off = 32; off > 0; off >>= 1) s += __shfl_xor(s, off, 64);
    __shared__ float sl[4];
    if (lane == 0) sl[w] = s;
    __syncthreads();
    if (tid == 0) out[0] = sl[0] + sl[1] + sl[2] + sl[3];
}

extern "C" void kernel_launch(void* const* d_in, const int* in_sizes, int n_in,
                              void* d_out, int out_size, void* d_ws, size_t ws_size,
                              hipStream_t stream) {
    const float* bu            = (const float*)d_in[0];
    const float* bi            = (const float*)d_in[1];
    const float* qi            = (const float*)d_in[2];
    const float* pu            = (const float*)d_in[3];
    const float* user_item_num = (const float*)d_in[4];
    const int*   users         = (const int*)d_in[5];
    const int*   pos_items     = (const int*)d_in[6];
    const int*   neg_items     = (const int*)d_in[7];
    const int*   hist_items    = (const int*)d_in[8];
    const int*   hist_segids   = (const int*)d_in[9];
    float* out  = (float*)d_out;

    int*   offs = (int*)d_ws;                         // BB+1 ints
    float* part = (float*)((char*)d_ws + (((BB + 2) * sizeof(int) + 255) & ~255)); // BB floats

    offs_kernel<<<(TOTAL_H + 255) / 256, 256, 0, stream>>>(hist_segids, offs);
    fism_kernel<<<BB, 256, 0, stream>>>(bu, bi, qi, pu, user_item_num,
                                        users, pos_items, neg_items,
                                        hist_items, offs, part);
    reduce_kernel<<<1, 256, 0, stream>>>(part, out);
}

// Round 6
// 129.155 us; speedup vs baseline: 1.5198x; 1.0042x over previous
//
#include <hip/hip_runtime.h>
#include <math.h>

#define ALPHA   0.5f
#define BATA    0.01f
#define LAMDA   0.01f
#define GAMA    0.01f
#define BB      4096
#define N_NEG   50
#define TOTAL_H 204800
#define DIM     64

// ---------------- phase 0: segment offsets
// offs[b] = first index i with hist_segids[i] >= b ; offs[BB] = TOTAL_H.
__global__ __launch_bounds__(256) void offs_kernel(
    const int* __restrict__ segids, int* __restrict__ offs)
{
    int i = blockIdx.x * 256 + threadIdx.x;
    if (i >= TOTAL_H) return;
    int s = segids[i];
    if (i == 0) {
        for (int b = 0; b <= s; ++b) offs[b] = 0;
    } else {
        int p = segids[i - 1];
        for (int b = p + 1; b <= s; ++b) offs[b] = i;
    }
    if (i == TOTAL_H - 1) {
        for (int b = s + 1; b <= BB; ++b) offs[b] = TOTAL_H;
    }
}

// ---------------- main: one 256-thread block (4 waves) per user.
// 16-lane groups (g = tid/16, sub = tid%16); lane sub owns dims [4*sub,4*sub+4).
// 4 masked hist slots (covers count<=64, ~98% of blocks); uniform-branch guard
// loop for bigger histories. Register budget kept <=64 VGPR for 8 waves/SIMD.
__global__ __launch_bounds__(256) void fism_kernel(
    const float* __restrict__ bu, const float* __restrict__ bi,
    const float* __restrict__ qi, const float* __restrict__ pu,
    const float* __restrict__ user_item_num,
    const int*  __restrict__ users, const int* __restrict__ pos_items,
    const int*  __restrict__ neg_items, const int* __restrict__ hist_items,
    const int*  __restrict__ offs,
    float* __restrict__ part)
{
    const int b    = blockIdx.x;
    const int tid  = threadIdx.x;
    const int lane = tid & 63;
    const int w    = tid >> 6;
    const int g    = tid >> 4;
    const int sub  = tid & 15;

    __shared__ float4 s_part[64];
    __shared__ float  s_loss[4];

    const float4* pu4 = (const float4*)pu;
    const float4* qi4 = (const float4*)qi;

    const int start = offs[b];
    const int end   = offs[b + 1];

    // ---- tier 1: all index / scalar loads (independent)
    const int* nrow = neg_items + (size_t)b * N_NEG;
    int  nidx[4];
    bool nv[4];
    #pragma unroll
    for (int k = 0; k < 4; ++k) {
        int j = g + 16 * k;
        nv[k]   = (j < N_NEG);
        nidx[k] = nrow[nv[k] ? j : 0];
    }
    const int   pit = pos_items[b];
    const float t   = rsqrtf(user_item_num[b]);
    const float b_u = bu[users[b]];

    // 4 masked hist indices per group (covers count <= 64)
    int   hidx[4];
    float hm[4];
    #pragma unroll
    for (int k = 0; k < 4; ++k) {
        int ip  = start + g + 16 * k;
        bool v  = (ip < end);
        hm[k]   = v ? 1.f : 0.f;
        hidx[k] = hist_items[v ? ip : (TOTAL_H - 1)];
    }

    // ---- tier 2: all row gathers, issued in consumption order
    float4 acc = make_float4(0.f, 0.f, 0.f, 0.f);
    #pragma unroll
    for (int k = 0; k < 4; ++k) {
        float4 r = pu4[(size_t)hidx[k] * 16 + sub];
        acc.x += hm[k] * r.x; acc.y += hm[k] * r.y;
        acc.z += hm[k] * r.z; acc.w += hm[k] * r.w;
    }
    const float4 qp  = qi4[(size_t)pit * 16 + sub];
    const float  bip = bi[pit];
    float4 nq[4];
    float  nb[4];
    #pragma unroll
    for (int k = 0; k < 4; ++k) {
        nq[k] = qi4[(size_t)nidx[k] * 16 + sub];
        nb[k] = bi[nidx[k]];
    }
    // block-uniform slow path: histories > 64 (~2% of blocks)
    if (end - start > 64) {
        for (int i = start + g + 64; i < end; i += 16) {
            float4 r = pu4[(size_t)hist_items[i] * 16 + sub];
            acc.x += r.x; acc.y += r.y; acc.z += r.z; acc.w += r.w;
        }
    }

    // reduce the 4 groups within this wave (xor lane bits 4,5)
    #pragma unroll
    for (int off = 16; off < 64; off <<= 1) {
        acc.x += __shfl_xor(acc.x, off, 64);
        acc.y += __shfl_xor(acc.y, off, 64);
        acc.z += __shfl_xor(acc.z, off, 64);
        acc.w += __shfl_xor(acc.w, off, 64);
    }
    if (lane < 16) s_part[w * 16 + lane] = acc;
    __syncthreads();

    float4 full = s_part[sub];
    {
        float4 p1 = s_part[16 + sub], p2 = s_part[32 + sub], p3 = s_part[48 + sub];
        full.x += p1.x + p2.x + p3.x;
        full.y += p1.y + p2.y + p3.y;
        full.z += p1.z + p2.z + p3.z;
        full.w += p1.w + p2.w + p3.w;
    }

    float loss = 0.f;

    // ---- positive + per-user regularization
    {
        float pdot = full.x * qp.x + full.y * qp.y + full.z * qp.z + full.w * qp.w;
        float psq  = qp.x * qp.x + qp.y * qp.y + qp.z * qp.z + qp.w * qp.w;
        float uesq = full.x * full.x + full.y * full.y + full.z * full.z + full.w * full.w;
        #pragma unroll
        for (int off = 1; off < 16; off <<= 1) {
            pdot += __shfl_xor(pdot, off, 64);
            psq  += __shfl_xor(psq,  off, 64);
            uesq += __shfl_xor(uesq, off, 64);
        }
        if (tid == 0) {
            float s = 1.f / (1.f + __expf(-(t * pdot + bip + b_u)));
            loss += (1.f - s) * (1.f - s);
            loss += BATA * uesq + BATA * psq;
            loss += LAMDA * (bip * bip + GAMA * b_u * b_u);
        }
    }

    // ---- negatives: rows already in registers; 4 interleaved reduce chains
    {
        float d0 = full.x * nq[0].x + full.y * nq[0].y + full.z * nq[0].z + full.w * nq[0].w;
        float d1 = full.x * nq[1].x + full.y * nq[1].y + full.z * nq[1].z + full.w * nq[1].w;
        float d2 = full.x * nq[2].x + full.y * nq[2].y + full.z * nq[2].z + full.w * nq[2].w;
        float d3 = full.x * nq[3].x + full.y * nq[3].y + full.z * nq[3].z + full.w * nq[3].w;
        #pragma unroll
        for (int off = 1; off < 16; off <<= 1) {
            d0 += __shfl_xor(d0, off, 64);
            d1 += __shfl_xor(d1, off, 64);
            d2 += __shfl_xor(d2, off, 64);
            d3 += __shfl_xor(d3, off, 64);
        }
        if (sub == 0) {
            float s0 = 1.f / (1.f + __expf(-(t * d0 + nb[0] + b_u)));
            float s1 = 1.f / (1.f + __expf(-(t * d1 + nb[1] + b_u)));
            float s2 = 1.f / (1.f + __expf(-(t * d2 + nb[2] + b_u)));
            float s3 = 1.f / (1.f + __expf(-(t * d3 + nb[3] + b_u)));
            if (nv[0]) loss += s0 * s0;
            if (nv[1]) loss += s1 * s1;
            if (nv[2]) loss += s2 * s2;
            if (nv[3]) loss += s3 * s3;
        }
    }

    // ---- block loss reduction: only lanes 0/16/32/48 are nonzero -> 2 levels
    loss += __shfl_xor(loss, 16, 64);
    loss += __shfl_xor(loss, 32, 64);
    if (lane == 0) s_loss[w] = loss;
    __syncthreads();
    if (tid == 0) part[b] = s_loss[0] + s_loss[1] + s_loss[2] + s_loss[3];
}

// ---------------- final: sum 4096 partials -> out[0] (single block, no atomics)
__global__ __launch_bounds__(256) void reduce_kernel(
    const float* __restrict__ part, float* __restrict__ out)
{
    const int tid  = threadIdx.x;
    const int lane = tid & 63;
    const int w    = tid >> 6;
    float s = 0.f;
    #pragma unroll
    for (int i = 0; i < BB / 256; ++i) s += part[tid + i * 256];
    #pragma unroll
    for (int off = 32; off > 0; off >>= 1) s += __shfl_xor(s, off, 64);
    __shared__ float sl[4];
    if (lane == 0) sl[w] = s;
    __syncthreads();
    if (tid == 0) out[0] = sl[0] + sl[1] + sl[2] + sl[3];
}

extern "C" void kernel_launch(void* const* d_in, const int* in_sizes, int n_in,
                              void* d_out, int out_size, void* d_ws, size_t ws_size,
                              hipStream_t stream) {
    const float* bu            = (const float*)d_in[0];
    const float* bi            = (const float*)d_in[1];
    const float* qi            = (const float*)d_in[2];
    const float* pu            = (const float*)d_in[3];
    const float* user_item_num = (const float*)d_in[4];
    const int*   users         = (const int*)d_in[5];
    const int*   pos_items     = (const int*)d_in[6];
    const int*   neg_items     = (const int*)d_in[7];
    const int*   hist_items    = (const int*)d_in[8];
    const int*   hist_segids   = (const int*)d_in[9];
    float* out  = (float*)d_out;

    int*   offs = (int*)d_ws;                         // BB+1 ints
    float* part = (float*)((char*)d_ws + (((BB + 2) * sizeof(int) + 255) & ~255)); // BB floats

    offs_kernel<<<(TOTAL_H + 255) / 256, 256, 0, stream>>>(hist_segids, offs);
    fism_kernel<<<BB, 256, 0, stream>>>(bu, bi, qi, pu, user_item_num,
                                        users, pos_items, neg_items,
                                        hist_items, offs, part);
    reduce_kernel<<<1, 256, 0, stream>>>(part, out);
}